// Round 5
// baseline (625.907 us; speedup 1.0000x reference)
//
#include <hip/hip_runtime.h>
#include <math.h>

typedef unsigned short u16;
typedef unsigned int u32;
typedef __bf16 bf16x8 __attribute__((ext_vector_type(8)));
typedef float f32x4 __attribute__((ext_vector_type(4)));

#define BM 128
#define BN 128
#define BK 32

__device__ __forceinline__ u16 f2b(float f) {
    u32 u = __float_as_uint(f);
    return (u16)((u + 0x7FFFu + ((u >> 16) & 1u)) >> 16);
}
__device__ __forceinline__ float b2f(u16 h) {
    return __uint_as_float(((u32)h) << 16);
}

// async global->LDS, 16B per lane. LDS dest is wave-uniform base + lane*16.
#define GLL16(gp, lp)                                                          \
    __builtin_amdgcn_global_load_lds(                                          \
        (__attribute__((address_space(1))) void*)(const_cast<u16*>(gp)),       \
        (__attribute__((address_space(3))) void*)(lp), 16, 0, 0)

// ---------------------------------------------------------------------------
// NT GEMM: A [M x K] row-major, B [N x K] row-major (B^T input), D [M x N]
// EPI: 0 = +bias, pair-rotate -> bf16 (QKV; v-group stores transposed to D2
//          via LDS-staged coalesced stores)
//      1 = softplus(scale*x) causal-masked -> bf16
//      2 = inverse pair-rotate -> bf16
//      3 = +bias -> f32
// KLIM:  truncate K-loop at r0+BM (causal: only s <= t_max contribute)
// SWZ:   XCD-aware block swizzle from 1-D grid (consecutive blocks -> XCDs
//        round-robin, so a data-sharing GROUP sits at fixed n%8).
//        SWZ=0: group = by (row tile), bx = within, bz = 0.   WB = #bx tiles
//        SWZ=1: group = bz (batch),    w  = within, bx=w&7, by=w>>3. WB = 64
//        SWZ=2: group = bz (batch),    w  = within -> triangular (bx<=by),
//               WB = 36 (T/BM=8 row tiles -> 36 lower-tri tiles)
// SPLIT: column tiles 0..7 -> D0 (k), 8..15 -> D1 (q), 16..23 -> D2 (vT).
// cossin: packed per-pair {lo: cos bf16, hi: sin bf16}; row = global row for
//         EPI=0 (M spans b,t), (bz*1024+row) for EPI=2.
// ---------------------------------------------------------------------------
template <int EPI, bool KLIM, int SWZ, bool SPLIT>
__global__ __launch_bounds__(256) void gemm_nt(
    const u16* __restrict__ A, long long sAz,
    const u16* __restrict__ B, long long sBz,
    void* __restrict__ D0, void* __restrict__ D1, void* __restrict__ D2,
    long long sDz,
    const float* __restrict__ bias0, const float* __restrict__ bias1,
    const float* __restrict__ bias2,
    const u32* __restrict__ cossin,
    int M, int N, int K, float scale, int WB)
{
    int bx, by, bz;
    {
        const int n = blockIdx.x;
        const int xcd = n & 7, m = n >> 3;
        if (SWZ == 0) {
            by = xcd + 8 * (m / WB);
            bx = m % WB;
            bz = 0;
        } else if (SWZ == 1) {
            bz = xcd + 8 * (m / WB);
            const int w = m % WB;
            bx = w & 7;
            by = w >> 3;
        } else {
            bz = xcd + 8 * (m / WB);
            const int w = m % WB;
            int r = (int)((sqrtf(8.f * w + 1.f) - 1.f) * 0.5f);
            while ((r + 1) * (r + 2) / 2 <= w) r++;
            while (r * (r + 1) / 2 > w) r--;
            by = r;
            bx = w - r * (r + 1) / 2;
        }
    }
    const int r0 = by * BM, c0 = bx * BN;

    // single LDS pool: As = sh[0:4096], Bs = sh[4096:8192]; reused by the
    // v-transpose epilogue after the K-loop.
    __shared__ __align__(16) u16 sh[BM * BK + BN * BK];
    u16* As = sh;
    u16* Bs = sh + BM * BK;

    const int tid = threadIdx.x;
    const int lane = tid & 63, wave = tid >> 6;
    const int wm = (wave >> 1) * 64, wn = (wave & 1) * 64;

    const u16* Ab = A + (long long)bz * sAz + (long long)r0 * K;
    const u16* Bb = B + (long long)bz * sBz + (long long)c0 * K;

    const int ra0 = tid >> 2;          // row 0..63 (second issue: +64)
    const int ca0 = (tid & 3) * 8;     // k-chunk within row

    f32x4 acc[4][4];
    #pragma unroll
    for (int i = 0; i < 4; i++)
        #pragma unroll
        for (int j = 0; j < 4; j++)
            acc[i][j] = (f32x4){0.f, 0.f, 0.f, 0.f};

    const int kEnd = KLIM ? ((r0 + BM) < K ? (r0 + BM) : K) : K;

    for (int k0 = 0; k0 < kEnd; k0 += BK) {
        GLL16(Ab + (long long)ra0 * K + k0 + ca0,        &As[tid * 8]);
        GLL16(Ab + (long long)(ra0 + 64) * K + k0 + ca0, &As[(tid + 256) * 8]);
        GLL16(Bb + (long long)ra0 * K + k0 + ca0,        &Bs[tid * 8]);
        GLL16(Bb + (long long)(ra0 + 64) * K + k0 + ca0, &Bs[(tid + 256) * 8]);
        __syncthreads();

        bf16x8 af[4], bfv[4];
        #pragma unroll
        for (int i = 0; i < 4; i++) {
            af[i]  = *(const bf16x8*)&As[(wm + i * 16 + (lane & 15)) * BK + (lane >> 4) * 8];
            bfv[i] = *(const bf16x8*)&Bs[(wn + i * 16 + (lane & 15)) * BK + (lane >> 4) * 8];
        }
        #pragma unroll
        for (int i = 0; i < 4; i++)
            #pragma unroll
            for (int j = 0; j < 4; j++)
                acc[i][j] = __builtin_amdgcn_mfma_f32_16x16x32_bf16(af[i], bfv[j], acc[i][j], 0, 0, 0);
        __syncthreads();
    }

    // output routing (uniform per block)
    void* Dp = D0;
    const float* bp_ = bias0;
    int ldD = N, cbase = c0, sel = 0;
    if (SPLIT) {
        sel = bx >> 3;                 // 8 tiles per 1024-col group
        Dp  = (sel == 0) ? D0 : (sel == 1) ? D1 : D2;
        bp_ = (sel == 0) ? bias0 : (sel == 1) ? bias1 : bias2;
        ldD = 1024;
        cbase = c0 & 1023;
    }

    // epilogue: C/D layout col=lane&15, row=(lane>>4)*4+reg
    const int rl = (lane >> 4) * 4, cl = lane & 15;

    if (EPI == 0 && sel == 2) {
        // v group: bias + rotate, then LDS-staged transpose -> coalesced
        // stores into vT[b][c][t]. Two half-passes of 64 columns (16 KB).
        const int bb = r0 >> 10, tloc = r0 & 1023;
        #pragma unroll
        for (int p = 0; p < 2; p++) {
            if ((wave & 1) == p) {     // waves with wn == 64*p stage
                #pragma unroll
                for (int i = 0; i < 4; i++) {
                    #pragma unroll
                    for (int j = 0; j < 4; j++) {
                        const int t0 = wm + i * 16 + rl;       // 4-aligned
                        const int c_loc = j * 16 + cl;          // 0..63
                        const int gcd = cbase + 64 * p + c_loc; // v column
                        u16 pk[4];
                        #pragma unroll
                        for (int v = 0; v < 4; v++) {
                            const int gr = r0 + t0 + v;
                            float my = acc[i][j][v] + bp_[gcd];
                            float other = __shfl_xor(my, 1);
                            u32 csn = cossin[(long long)gr * 512 + (gcd >> 1)];
                            float cs = b2f((u16)(csn & 0xffff)), sn = b2f((u16)(csn >> 16));
                            float res = (gcd & 1) ? (sn * other + cs * my)
                                                  : (cs * my - sn * other);
                            pk[v] = f2b(res);
                        }
                        // XOR-rotated layout: phys_t = (t + 8*(c&15)) & 127
                        const int phys = c_loc * 128 + ((t0 + 8 * (c_loc & 15)) & 127);
                        uint2 pw;
                        pw.x = (u32)pk[0] | ((u32)pk[1] << 16);
                        pw.y = (u32)pk[2] | ((u32)pk[3] << 16);
                        *(uint2*)&sh[phys] = pw;
                    }
                }
            }
            __syncthreads();
            // all waves: read back 16B chunks, coalesced 256B runs per column
            #pragma unroll
            for (int r = 0; r < 4; r++) {
                const int item = r * 256 + tid;
                const int c_loc = item >> 4, chunk = item & 15;
                const int t0 = chunk * 8;
                const int phys = c_loc * 128 + ((t0 + 8 * (c_loc & 15)) & 127);
                uint4 val = *(const uint4*)&sh[phys];
                const int gc = cbase + 64 * p + c_loc;
                const long long dst = ((((long long)bb << 10) + gc) << 10) + tloc + t0;
                *(uint4*)((u16*)Dp + dst) = val;
            }
            if (p == 0) __syncthreads();
        }
        return;
    }

    #pragma unroll
    for (int i = 0; i < 4; i++) {
        #pragma unroll
        for (int j = 0; j < 4; j++) {
            const int gr0 = r0 + wm + i * 16 + rl;
            const int gc  = wn + j * 16 + cl;          // col within tile span
            const int gcd = cbase + gc;                // col in D
            const int gcm = c0 + gc;                   // col for causal mask
            #pragma unroll
            for (int v = 0; v < 4; v++) {
                const int gr = gr0 + v;
                float val = acc[i][j][v];
                const long long o = (long long)bz * sDz + (long long)gr * ldD + gcd;
                if (EPI == 0) {
                    float my = val + bp_[gcd];
                    float other = __shfl_xor(my, 1);
                    u32 csn = cossin[(long long)gr * 512 + (gcd >> 1)];
                    float cs = b2f((u16)(csn & 0xffff)), sn = b2f((u16)(csn >> 16));
                    float res = (gcd & 1) ? (sn * other + cs * my)
                                          : (cs * my - sn * other);
                    ((u16*)Dp)[o] = f2b(res);
                } else if (EPI == 1) {
                    float xs = val * scale;
                    float r = (gcm <= gr) ? ((xs > 15.f) ? xs : log1pf(__expf(xs))) : 0.f;
                    ((u16*)Dp)[o] = f2b(r);
                } else if (EPI == 2) {
                    float my = val;
                    float other = __shfl_xor(my, 1);
                    u32 csn = cossin[((long long)((bz << 10) + gr)) * 512 + (gcd >> 1)];
                    float cs = b2f((u16)(csn & 0xffff)), sn = b2f((u16)(csn >> 16));
                    float res = (gcd & 1) ? (cs * my - sn * other)
                                          : (cs * my + sn * other);
                    ((u16*)Dp)[o] = f2b(res);
                } else {
                    ((float*)Dp)[o] = val + bp_[gcd];
                }
            }
        }
    }
}

// ---------------------------------------------------------------------------
// fp32 -> bf16 conversion, vectorized x4
// ---------------------------------------------------------------------------
__global__ void f2b_kern(const float* __restrict__ in, u16* __restrict__ out, int n4) {
    int i = blockIdx.x * blockDim.x + threadIdx.x;
    if (i >= n4) return;
    float4 f = ((const float4*)in)[i];
    uint2 o;
    o.x = (u32)f2b(f.x) | ((u32)f2b(f.y) << 16);
    o.y = (u32)f2b(f.z) | ((u32)f2b(f.w) << 16);
    ((uint2*)out)[i] = o;
}

// 4 weight matrices in one launch (blockIdx.y selects)
__global__ void f2b_w4(const float* __restrict__ a, const float* __restrict__ b,
                       const float* __restrict__ c, const float* __restrict__ d,
                       u16* __restrict__ oa, u16* __restrict__ ob,
                       u16* __restrict__ oc, u16* __restrict__ od, int n4) {
    int i = blockIdx.x * blockDim.x + threadIdx.x;
    if (i >= n4) return;
    const float* src = (blockIdx.y == 0) ? a : (blockIdx.y == 1) ? b
                     : (blockIdx.y == 2) ? c : d;
    u16* dst = (blockIdx.y == 0) ? oa : (blockIdx.y == 1) ? ob
             : (blockIdx.y == 2) ? oc : od;
    float4 f = ((const float4*)src)[i];
    uint2 o;
    o.x = (u32)f2b(f.x) | ((u32)f2b(f.y) << 16);
    o.y = (u32)f2b(f.z) | ((u32)f2b(f.w) << 16);
    ((uint2*)dst)[i] = o;
}

// ---------------------------------------------------------------------------
// Angle suffix-sum (angle[t] = sum_{s>=t} emb[idx[s]]) in 3 phases; phase 3
// emits packed bf16 {cos, sin}.
// ---------------------------------------------------------------------------
#define TT 1024
#define CC2 512
#define NCH 32
#define CL 32

__global__ void angle_partial(const int* __restrict__ idx, const float* __restrict__ emb,
                              float* __restrict__ partial) {
    int b = blockIdx.x >> 5, ch = blockIdx.x & 31;
    int c = threadIdx.x;               // 0..511
    float s = 0.f;
    int tb = ch * CL;
    for (int t = 0; t < CL; t++) {
        int row = idx[b * TT + tb + t];
        s += emb[(long long)row * CC2 + c];
    }
    partial[((long long)b * NCH + ch) * CC2 + c] = s;
}

__global__ void angle_scan(float* __restrict__ partial) {
    int b = blockIdx.x, c = threadIdx.x;
    float run = 0.f;
    for (int ch = NCH - 1; ch >= 0; ch--) {
        long long o = ((long long)b * NCH + ch) * CC2 + c;
        float p = partial[o];
        partial[o] = run;              // exclusive suffix (chunks after this one)
        run += p;
    }
}

__global__ void angle_final(const int* __restrict__ idx, const float* __restrict__ emb,
                            const float* __restrict__ partial,
                            u32* __restrict__ cossin) {
    int b = blockIdx.x >> 5, ch = blockIdx.x & 31;
    int c = threadIdx.x;
    float run = partial[((long long)b * NCH + ch) * CC2 + c];
    for (int t = CL - 1; t >= 0; t--) {
        int tt = ch * CL + t;
        int row = idx[b * TT + tt];
        run += emb[(long long)row * CC2 + c];
        float sn, cs;
        __sincosf(run, &sn, &cs);
        cossin[((long long)b * TT + tt) * CC2 + c] = (u32)f2b(cs) | ((u32)f2b(sn) << 16);
    }
}

// ---------------------------------------------------------------------------
extern "C" void kernel_launch(void* const* d_in, const int* in_sizes, int n_in,
                              void* d_out, int out_size, void* d_ws, size_t ws_size,
                              hipStream_t stream) {
    const int Bn = 16, T = 1024, C = 1024;
    const long long TC = (long long)T * C;
    const size_t nx = (size_t)Bn * T * C;          // 16,777,216
    const size_t npairs = nx / 2;                  // 8,388,608

    const float* x   = (const float*)d_in[0];
    const int*   idx = (const int*)d_in[1];
    const float* Wk  = (const float*)d_in[2];
    const float* bk  = (const float*)d_in[3];
    const float* Wq  = (const float*)d_in[4];
    const float* bq  = (const float*)d_in[5];
    const float* Wv  = (const float*)d_in[6];
    const float* bv  = (const float*)d_in[7];
    const float* Wp  = (const float*)d_in[8];
    const float* bp  = (const float*)d_in[9];
    const float* emb = (const float*)d_in[10];
    float* out = (float*)d_out;

    // workspace (~171 MB)
    u16* xb  = (u16*)d_ws;          // x bf16; aliased as wei after QKV
    u16* kb  = xb + nx;             // k (rotated by QKV epilogue)
    u16* qb  = kb + nx;             // q (rotated); y after GEMM-O
    u16* vT  = qb + nx;             // v rotated+transposed [B][C][T]
    u32* cossin = (u32*)(vT + nx);  // [B][T][512] packed bf16 {cos,sin}
    u16* Wall = (u16*)(cossin + npairs);           // [3072][1024] = Wk|Wq|Wv
    u16* Wpb  = Wall + (size_t)3 * C * C;
    float* partial = (float*)(Wpb + (size_t)C * C);  // [B][32][512]
    u16* wei = xb;                  // alias (x dead after QKV)

    // 1) conversions to bf16
    f2b_kern<<<(int)(nx / 4 / 256), 256, 0, stream>>>(x, xb, (int)(nx / 4));
    f2b_w4<<<dim3(C * C / 4 / 256, 4), 256, 0, stream>>>(
        Wk, Wq, Wv, Wp, Wall, Wall + (size_t)C * C, Wall + (size_t)2 * C * C, Wpb,
        C * C / 4);

    // 2) angle suffix-sum -> packed cos/sin
    angle_partial<<<Bn * NCH, 512, 0, stream>>>(idx, emb, partial);
    angle_scan<<<Bn, 512, 0, stream>>>(partial);
    angle_final<<<Bn * NCH, 512, 0, stream>>>(idx, emb, partial, cossin);

    // 3) fused QKV projection: M=16384, N=3072, K=1024; bias+rotate fused,
    //    v stored transposed (LDS-coalesced). XCD-swizzled by row tile.
    gemm_nt<0, false, 0, true><<<3072, 256, 0, stream>>>(
        xb, 0, Wall, 0, kb, qb, vT, 0, bk, bq, bv, cossin,
        Bn * T, 3 * C, C, 1.f, 24);

    // 4) wei = softplus(k @ q^T / 32), causal; triangular grid (36 tiles/batch)
    gemm_nt<1, false, 2, false><<<16 * 36, 256, 0, stream>>>(
        kb, TC, qb, TC, wei, nullptr, nullptr, (long long)T * T,
        nullptr, nullptr, nullptr, nullptr, T, T, C, 0.03125f, 36);

    // 5) attn = wei @ v with inverse-rotation epilogue -> y (qb);
    //    K truncated at causal boundary
    gemm_nt<2, true, 1, false><<<1024, 256, 0, stream>>>(
        wei, (long long)T * T, vT, (long long)C * T, qb, nullptr, nullptr, TC,
        nullptr, nullptr, nullptr, cossin, T, C, T, 1.f, 64);

    // 6) final projection -> f32 out; row-tile swizzle (WB=8)
    gemm_nt<3, false, 0, false><<<1024, 256, 0, stream>>>(
        qb, 0, Wpb, 0, out, nullptr, nullptr, 0, bp, nullptr, nullptr, nullptr,
        Bn * T, C, C, 1.f, 8);
}